// Round 13
// baseline (194.980 us; speedup 1.0000x reference)
//
#include <hip/hip_runtime.h>
#include <math.h>

#define B_   2
#define SQ_  2048
#define SK_  2048
#define DM_  1024
#define H_   16
#define D_   64

typedef __attribute__((ext_vector_type(8))) short bf16x8;
typedef __attribute__((ext_vector_type(4))) float f32x4;
typedef unsigned int u32;

// fp32 -> bf16 RNE
__device__ __forceinline__ short f2bf(float f) {
    union { float f; unsigned u; } v; v.f = f;
    unsigned r = v.u + 0x7FFFu + ((v.u >> 16) & 1u);
    return (short)(r >> 16);
}
// pack two fp32 -> two bf16 (round-half-up) in one u32 — VERIFIED semantics.
__device__ __forceinline__ u32 pk2bf(float x, float y) {
    union { float f; u32 u; } a, b; a.f = x; b.f = y;
    return ((a.u + 0x8000u) >> 16) | ((b.u + 0x8000u) & 0xFFFF0000u);
}
// Bit-exact v_perm form of pk2bf (3 VALU ops).
// (inline-asm v_cvt_pk_bf16_f32 broke correctness in R2 — do not use.)
__device__ __forceinline__ u32 pkbf_rh(float x, float y) {
    union { float f; u32 u; } a, b; a.f = x; b.f = y;
    return __builtin_amdgcn_perm(b.u + 0x8000u, a.u + 0x8000u, 0x07060302u);
}

__device__ __forceinline__ void gll16(const void* g, void* l) {
    __builtin_amdgcn_global_load_lds(
        (const __attribute__((address_space(1))) u32*)g,
        (__attribute__((address_space(3))) u32*)l, 16, 0, 0);
}

// ---------------------------------------------------------------------------
// prep: z=0..2 -> Wq/Wk/Wv [16,1024,64] f32 -> WT[h*64+d][m] bf16 (transposed)
//       z=3    -> Wo fp32 -> bf16 convert
//       z=4,5  -> x / x2 fp32 -> bf16 convert
// ---------------------------------------------------------------------------
__global__ __launch_bounds__(256) void prep_kernel(
    const float* __restrict__ Wq, const float* __restrict__ Wk,
    const float* __restrict__ Wv, const float* __restrict__ Wo,
    const float* __restrict__ x,  const float* __restrict__ x2,
    short* __restrict__ WqT, short* __restrict__ WkT,
    short* __restrict__ WvT, short* __restrict__ Wob,
    short* __restrict__ xb,  short* __restrict__ x2b)
{
    const int t = threadIdx.x;
    const int z = blockIdx.z;
    if (z >= 3) {
        const float* src = (z == 3) ? Wo : (z == 4) ? x : x2;
        short* dst       = (z == 3) ? Wob : (z == 4) ? xb : x2b;
        int nloop = (z == 3) ? 4 : 16;              // Wo: 1M floats; x: 4M
        int bid = blockIdx.y * 16 + blockIdx.x;     // 0..255
        #pragma unroll 4
        for (int j = 0; j < nloop; j++) {
            int i = bid * (nloop * 256) + j * 256 + t;   // float4 units
            float4 v = ((const float4*)src)[i];
            short4 s;
            s.x = f2bf(v.x); s.y = f2bf(v.y); s.z = f2bf(v.z); s.w = f2bf(v.w);
            ((short4*)dst)[i] = s;
        }
        return;
    }
    const float* W = (z == 0) ? Wq : (z == 1) ? Wk : Wv;
    short* WT      = (z == 0) ? WqT : (z == 1) ? WkT : WvT;
    const int h  = blockIdx.y;
    const int m0 = blockIdx.x * 64;
    __shared__ short Ls[64][68];

    #pragma unroll
    for (int it = 0; it < 4; it++) {
        int lin = it * 256 + t;         // float4 units, 1024 total
        int m = lin >> 4, d4 = lin & 15;
        float4 v = *(const float4*)&W[((long)h * DM_ + m0 + m) * D_ + d4 * 4];
        short4 s;
        s.x = f2bf(v.x); s.y = f2bf(v.y); s.z = f2bf(v.z); s.w = f2bf(v.w);
        *(short4*)&Ls[m][d4 * 4] = s;
    }
    __syncthreads();
    #pragma unroll
    for (int it = 0; it < 2; it++) {
        int d = (t >> 3) + it * 32, scol = t & 7;
        bf16x8 vv;
        #pragma unroll
        for (int j = 0; j < 8; j++) vv[j] = Ls[scol * 8 + j][d];
        *(bf16x8*)&WT[((long)h * 64 + d) * DM_ + m0 + scol * 8] = vv;
    }
}

// ---------------------------------------------------------------------------
// bf16 MFMA GEMM core, 128x128 tile, BK=64, gll16 + XOR swizzle,
// double-buffered LDS + one barrier per K-step (R9 verified — R12's
// kh-rotation was neutral-to-negative and was reverted).
// Epilogue: DIRECT global stores (R9) — R11's LDS round-trip regressed 6 us.
// NOTE (R8 lesson): do NOT XCD-swizzle this grid.
// ---------------------------------------------------------------------------
__device__ __forceinline__ void gemm_stage(
    short* __restrict__ Asb, short* __restrict__ Bsb,
    const short* __restrict__ A, const short* __restrict__ Bw,
    int r0, int n0, int k0c, int w, int srow, int sc)
{
    #pragma unroll
    for (int j = 0; j < 4; j++) {
        int q   = w * 4 + j;
        int row = q * 8 + srow;
        gll16(A  + ((long)(r0 + row) << 10) + k0c + sc * 8, Asb + q * 512);
        gll16(Bw + ((long)(n0 + row) << 10) + k0c + sc * 8, Bsb + q * 512);
    }
}

template <int MODE>
__device__ __forceinline__ void gemm_core(
    short* __restrict__ Ls,
    const short* __restrict__ A, const short* __restrict__ Bw,
    const float* __restrict__ bias, void* __restrict__ outp,
    int r0, int n0, float oscale)
{
    const int t    = threadIdx.x;
    const int w    = t >> 6;
    const int ln   = t & 63;
    const int l15  = ln & 15;
    const int quad = ln >> 4;
    const int wr   = w >> 1;
    const int wc   = w & 1;

    f32x4 acc[4][4];
    #pragma unroll
    for (int i = 0; i < 4; i++)
        #pragma unroll
        for (int j = 0; j < 4; j++) acc[i][j] = (f32x4){0.f, 0.f, 0.f, 0.f};

    const int srow = ln >> 3;
    const int sc   = (ln & 7) ^ srow;
    const int rsw  = l15 & 7;

    // prologue: stage k0=0 into buffer 0
    gemm_stage(Ls, Ls + 8192, A, Bw, r0, n0, 0, w, srow, sc);

    int cur = 0;
    for (int k0 = 0; k0 < 1024; k0 += 64) {
        __syncthreads();            // buf[cur] staged; prev reads drained
        if (k0 + 64 < 1024) {
            short* Anx = Ls + (cur ^ 1) * 16384;
            gemm_stage(Anx, Anx + 8192, A, Bw, r0, n0, k0 + 64, w, srow, sc);
        }
        const short* Asb = Ls + cur * 16384;
        const short* Bsb = Asb + 8192;
        #pragma unroll
        for (int kh = 0; kh < 2; kh++) {
            bf16x8 af[4], bfr[4];
            #pragma unroll
            for (int i = 0; i < 4; i++) {
                int ra = wr * 64 + i * 16 + l15;
                int rb = wc * 64 + i * 16 + l15;
                int pc = ((kh * 4 + quad) ^ rsw) * 8;
                af[i]  = *(const bf16x8*)&Asb[ra * 64 + pc];
                bfr[i] = *(const bf16x8*)&Bsb[rb * 64 + pc];
            }
            #pragma unroll
            for (int i = 0; i < 4; i++)
                #pragma unroll
                for (int j = 0; j < 4; j++)
                    acc[i][j] = __builtin_amdgcn_mfma_f32_16x16x32_bf16(
                        af[i], bfr[j], acc[i][j], 0, 0, 0);
        }
        cur ^= 1;
    }

    #pragma unroll
    for (int j = 0; j < 4; j++) {
        int col = n0 + wc * 64 + j * 16 + l15;
        float bv = bias[col];
        if (MODE == 2) {
            // VT[((b*16+h)*64 + d)][sp], 4 consecutive s per lane (short4).
            // sp = tile-local sigma^{-1}(s): bits (5,4,3,2,1,0) <- (s5,s3,s2,s4,s1,s0)
            int hh = col >> 6, dd = col & 63;
            #pragma unroll
            for (int i = 0; i < 4; i++) {
                int rowb = r0 + wr * 64 + i * 16 + quad * 4;
                int bb = rowb >> 11, ss = rowb & 2047;
                int sl = ss & 63;
                int sp = (ss & ~63) | (sl & 35) | ((sl & 12) << 1) | ((sl & 16) >> 2);
                short4 sv;
                sv.x = f2bf(acc[i][j][0] + bv);
                sv.y = f2bf(acc[i][j][1] + bv);
                sv.z = f2bf(acc[i][j][2] + bv);
                sv.w = f2bf(acc[i][j][3] + bv);
                *(short4*)&((short*)outp)[
                    ((long)(((bb << 4) + hh) * 64 + dd) << 11) + sp] = sv;
            }
        } else {
            #pragma unroll
            for (int i = 0; i < 4; i++) {
                int rowb = r0 + wr * 64 + i * 16 + quad * 4;
                #pragma unroll
                for (int r = 0; r < 4; r++) {
                    float v = (acc[i][j][r] + bv) * oscale;
                    if (MODE == 0)
                        ((short*)outp)[(long)(rowb + r) * 1024 + col] = f2bf(v);
                    else
                        ((float*)outp)[(long)(rowb + r) * 1024 + col] = v;
                }
            }
        }
    }
}

// Q scale: 1/sqrt(64) * log2(e)  (flash uses raw v_exp_f32 = 2^x)
#define QSCALE 0.180336880977f

__global__ __launch_bounds__(256) void gemm_qkv_kernel(
    const short* __restrict__ x2b, const short* __restrict__ xb,
    const short* __restrict__ WqT, const short* __restrict__ WkT,
    const short* __restrict__ WvT,
    const float* __restrict__ bq, const float* __restrict__ bk,
    const float* __restrict__ bv,
    short* __restrict__ Qb, short* __restrict__ Kb, short* __restrict__ VT)
{
    __shared__ short Ls[2 * 16384];     // 64 KB, shared by all MODE branches
    const int z = blockIdx.z;
    if (z == 0) {
        gemm_core<0>(Ls, x2b, WqT, bq, Qb, blockIdx.x * 128, blockIdx.y * 128, QSCALE);
    } else if (z == 1) {
        gemm_core<0>(Ls, xb, WkT, bk, Kb, blockIdx.x * 128, blockIdx.y * 128, 1.0f);
    } else {
        gemm_core<2>(Ls, xb, WvT, bv, VT, blockIdx.x * 128, blockIdx.y * 128, 1.0f);
    }
}

// ---------------------------------------------------------------------------
// gemm_out: 64x128 tiles -> grid (64,8) = 512 blocks = 2 blocks/CU.
// Double-buffer + one-barrier-per-K-step pipeline (verified R7).
// ---------------------------------------------------------------------------
__device__ __forceinline__ void gout_stage(
    short* __restrict__ Asb, short* __restrict__ Bsb,
    const short* __restrict__ A, const short* __restrict__ Bw,
    int r0, int n0, int k0c, int w, int srow, int sc)
{
    #pragma unroll
    for (int j = 0; j < 6; j++) {           // 24 issues: 8 A + 16 B
        int q = w * 6 + j;
        if (q < 8) {
            int row = q * 8 + srow;
            gll16(A + ((long)(r0 + row) << 10) + k0c + sc * 8, Asb + q * 512);
        } else {
            int qb = q - 8;
            int row = qb * 8 + srow;
            gll16(Bw + ((long)(n0 + row) << 10) + k0c + sc * 8, Bsb + qb * 512);
        }
    }
}

__global__ __launch_bounds__(256) void gemm_out_kernel(
    const short* __restrict__ A, const short* __restrict__ Bw,
    const float* __restrict__ bias, float* __restrict__ outp)
{
    __shared__ short Ls[2 * 12288];     // 48 KB

    const int r0   = blockIdx.x * 64;
    const int n0   = blockIdx.y * 128;
    const int t    = threadIdx.x;
    const int w    = t >> 6;
    const int ln   = t & 63;
    const int l15  = ln & 15;
    const int quad = ln >> 4;
    const int wr   = w >> 1;            // row group (32 rows)
    const int wc   = w & 1;             // col group (64 cols)

    f32x4 acc[2][4];
    #pragma unroll
    for (int i = 0; i < 2; i++)
        #pragma unroll
        for (int j = 0; j < 4; j++) acc[i][j] = (f32x4){0.f, 0.f, 0.f, 0.f};

    const int srow = ln >> 3;
    const int sc   = (ln & 7) ^ srow;
    const int rsw  = l15 & 7;

    gout_stage(Ls, Ls + 4096, A, Bw, r0, n0, 0, w, srow, sc);

    int cur = 0;
    for (int k0 = 0; k0 < 1024; k0 += 64) {
        __syncthreads();
        if (k0 + 64 < 1024) {
            short* Anx = Ls + (cur ^ 1) * 12288;
            gout_stage(Anx, Anx + 4096, A, Bw, r0, n0, k0 + 64, w, srow, sc);
        }
        const short* Asb = Ls + cur * 12288;
        const short* Bsb = Asb + 4096;
        #pragma unroll
        for (int kh = 0; kh < 2; kh++) {
            int pc = ((kh * 4 + quad) ^ rsw) * 8;
            bf16x8 af[2], bfr[4];
            #pragma unroll
            for (int i = 0; i < 2; i++)
                af[i] = *(const bf16x8*)&Asb[(wr * 32 + i * 16 + l15) * 64 + pc];
            #pragma unroll
            for (int j = 0; j < 4; j++)
                bfr[j] = *(const bf16x8*)&Bsb[(wc * 64 + j * 16 + l15) * 64 + pc];
            #pragma unroll
            for (int i = 0; i < 2; i++)
                #pragma unroll
                for (int j = 0; j < 4; j++)
                    acc[i][j] = __builtin_amdgcn_mfma_f32_16x16x32_bf16(
                        af[i], bfr[j], acc[i][j], 0, 0, 0);
        }
        cur ^= 1;
    }

    #pragma unroll
    for (int j = 0; j < 4; j++) {
        int col = n0 + wc * 64 + j * 16 + l15;
        float bv = bias[col];
        #pragma unroll
        for (int i = 0; i < 2; i++) {
            int rowb = r0 + wr * 32 + i * 16 + quad * 4;
            #pragma unroll
            for (int r = 0; r < 4; r++)
                outp[(long)(rowb + r) * 1024 + col] = acc[i][j][r] + bv;
        }
    }
}

// ---------------------------------------------------------------------------
// MFMA flash attention, FINE-GRAINED BLOCKS (R13):
// 64 q rows/block = 2 waves x 32 q (2 qg), 128 threads, grid 1024 blocks ->
// 4 blocks/CU (vs R9's 2x 4-wave blocks). Same per-wave work and LDS reads;
// barriers now sync only 2 waves, and 4 independent blocks/CU slide in
// phase to cover each other's barrier drains (m114 mechanism).
// KVBLK=64 single-tile double-buffer (32 KB LDS). Deferred tail retained:
// tile i's PV+l (pure-register) execute under tile i+1's K-frag reads.
// R10 lesson (do not widen q/wave) still honored: 32 q/wave.
// ---------------------------------------------------------------------------
__global__ __launch_bounds__(128, 2) void flash_kernel(
    const short* __restrict__ Q, const short* __restrict__ K,
    const short* __restrict__ VT, short* __restrict__ O)
{
    const int t    = threadIdx.x;
    const int wave = t >> 6;                // 0..1
    const int ln   = t & 63;
    const int l15  = ln & 15;
    const int quad = ln >> 4;
    // XCD swizzle (bijective, 1024 % 8 == 0): 128 consecutive work-ids
    // (= 4 complete bh) per XCD -> 2 MB K/V in the 4 MB XCD L2.
    const int f   = blockIdx.x + (blockIdx.y << 5);
    const int wid = ((f & 7) << 7) | (f >> 3);
    const int bh  = wid >> 5;
    const int b   = bh >> 4;
    const int h   = bh & 15;
    const int q0  = (wid & 31) * 64;
    const int wq  = q0 + wave * 32;         // this wave's first q row

    __shared__ short Ks[2][64 * 64];        // [buf][kpos][d]
    __shared__ short Vs[2][64 * 64];        // [buf][d][kpos(sigma)]

    const int srow = ln >> 3;               // row within 8-row staging chunk
    const int sc   = (ln & 7) ^ srow;       // swizzled source chunk (16B)
    const int rsw  = l15 & 7;               // read-side swizzle key
    const int pc0  = ((quad    ) ^ rsw) * 8;
    const int pc1  = ((quad + 4) ^ rsw) * 8;
    const int rb   = l15 * 64;              // fragment row base

    // Q B-frags (pre-scaled by 0.125*log2e): 2 q-groups
    bf16x8 aQ0[2], aQ1[2];
    #pragma unroll
    for (int qg = 0; qg < 2; qg++) {
        const short* Qp = Q + ((long)(b * SQ_ + wq + qg * 16 + l15)) * 1024
                            + h * 64 + quad * 8;
        aQ0[qg] = *(const bf16x8*)(Qp);
        aQ1[qg] = *(const bf16x8*)(Qp + 32);
    }

    bf16x8 ones;
    #pragma unroll
    for (int j = 0; j < 8; j++) ones[j] = (short)0x3F80;   // bf16 1.0

    const f32x4 fz = (f32x4){0.f, 0.f, 0.f, 0.f};   // shared zero C-in

    f32x4 o_acc[2][4];
    f32x4 l_acc[2];
    #pragma unroll
    for (int qg = 0; qg < 2; qg++) {
        l_acc[qg] = fz;
        #pragma unroll
        for (int i = 0; i < 4; i++) o_acc[qg][i] = fz;
    }

    const short* Kbase = K  + ((long)b * SK_) * 1024 + h * 64;
    const short* Vbase = VT + (long)bh * D_ * SK_;

    // stage one 64-k tile: wave w stages chunks w*4..w*4+3 of K and V
    #define STAGE(bufp, kbase)                                                  \
        _Pragma("unroll")                                                       \
        for (int j_ = 0; j_ < 4; j_++) {                                        \
            int qq_  = wave * 4 + j_;                                           \
            int row_ = qq_ * 8 + srow;                                          \
            gll16(Kbase + (long)((kbase) + row_) * 1024 + sc * 8,               \
                  &Ks[bufp][qq_ * 512]);                                        \
            gll16(Vbase + (long)row_ * 2048 + (kbase) + sc * 8,                 \
                  &Vs[bufp][qq_ * 512]);                                        \
        }

    // prologue: stage k-tile 0 into buffer 0
    STAGE(0, 0)

    // loop-carried deferred state (written in tile i, consumed in i+1)
    u32 pwB[2][8];
    bf16x8 vfB[8];

    int cur = 0;
    for (int k0 = 0; k0 < SK_; k0 += 64) {
        __syncthreads();
        if (k0 + 64 < SK_) {
            STAGE(cur ^ 1, k0 + 64)
        }
        const short* K0 = &Ks[cur][0];
        const short* V0 = &Vs[cur][0];

        // ---- issue K fragment reads ----
        bf16x8 kf[8];
        #pragma unroll
        for (int kt = 0; kt < 4; kt++) {
            const short* kr = &K0[kt * 1024 + rb];
            kf[kt * 2    ] = *(const bf16x8*)&kr[pc0];
            kf[kt * 2 + 1] = *(const bf16x8*)&kr[pc1];
        }

        // ---- deferred PV + l of PREVIOUS tile (registers only) ----
        if (k0) {
            bf16x8 aP0B[2], aP1B[2];
            #pragma unroll
            for (int qg = 0; qg < 2; qg++) {
                union { bf16x8 v; u32 w[4]; } u0, u1;
                u0.w[0] = pwB[qg][0]; u0.w[1] = pwB[qg][1];
                u0.w[2] = pwB[qg][2]; u0.w[3] = pwB[qg][3];
                u1.w[0] = pwB[qg][4]; u1.w[1] = pwB[qg][5];
                u1.w[2] = pwB[qg][6]; u1.w[3] = pwB[qg][7];
                aP0B[qg] = u0.v; aP1B[qg] = u1.v;
            }
            __builtin_amdgcn_s_setprio(1);
            #pragma unroll
            for (int qg = 0; qg < 2; qg++) {
                l_acc[qg] = __builtin_amdgcn_mfma_f32_16x16x32_bf16(aP0B[qg], ones, l_acc[qg], 0, 0, 0);
                l_acc[qg] = __builtin_amdgcn_mfma_f32_16x16x32_bf16(aP1B[qg], ones, l_acc[qg], 0, 0, 0);
            }
            #pragma unroll
            for (int dt = 0; dt < 4; dt++) {
                #pragma unroll
                for (int qg = 0; qg < 2; qg++) {
                    o_acc[qg][dt] = __builtin_amdgcn_mfma_f32_16x16x32_bf16(aP0B[qg], vfB[dt * 2    ], o_acc[qg][dt], 0, 0, 0);
                    o_acc[qg][dt] = __builtin_amdgcn_mfma_f32_16x16x32_bf16(aP1B[qg], vfB[dt * 2 + 1], o_acc[qg][dt], 0, 0, 0);
                }
            }
            __builtin_amdgcn_s_setprio(0);
        }

        // ---- QK on kf ----
        f32x4 z[2][4];
        #pragma unroll
        for (int kt = 0; kt < 4; kt++)
            #pragma unroll
            for (int qg = 0; qg < 2; qg++) {
                f32x4 zz = __builtin_amdgcn_mfma_f32_16x16x32_bf16(kf[kt * 2], aQ0[qg], fz, 0, 0, 0);
                z[qg][kt] = __builtin_amdgcn_mfma_f32_16x16x32_bf16(kf[kt * 2 + 1], aQ1[qg], zz, 0, 0, 0);
            }

        // ---- issue V fragment reads (consumed next tile) ----
        #pragma unroll
        for (int dt = 0; dt < 4; dt++) {
            const short* vr = &V0[dt * 1024 + rb];
            vfB[dt * 2    ] = *(const bf16x8*)&vr[pc0];
            vfB[dt * 2 + 1] = *(const bf16x8*)&vr[pc1];
        }

        // ---- exp2 + pack -> pwB (VALU; hides V-read latency) ----
        #pragma unroll
        for (int kt = 0; kt < 4; kt++)
            #pragma unroll
            for (int qg = 0; qg < 2; qg++) {
                f32x4 s = z[qg][kt];
                pwB[qg][kt * 2    ] = pkbf_rh(__builtin_amdgcn_exp2f(s[0]),
                                              __builtin_amdgcn_exp2f(s[1]));
                pwB[qg][kt * 2 + 1] = pkbf_rh(__builtin_amdgcn_exp2f(s[2]),
                                              __builtin_amdgcn_exp2f(s[3]));
            }

        cur ^= 1;
    }
    #undef STAGE

    // ---- final deferred PV + l ----
    {
        bf16x8 aP0B[2], aP1B[2];
        #pragma unroll
        for (int qg = 0; qg < 2; qg++) {
            union { bf16x8 v; u32 w[4]; } u0, u1;
            u0.w[0] = pwB[qg][0]; u0.w[1] = pwB[qg][1];
            u0.w[2] = pwB[qg][2]; u0.w[3] = pwB[qg][3];
            u1.w[0] = pwB[qg][4]; u1.w[1] = pwB[qg][5];
            u1.w[2] = pwB[qg][6]; u1.w[3] = pwB[qg][7];
            aP0B[qg] = u0.v; aP1B[qg] = u1.v;
            l_acc[qg] = __builtin_amdgcn_mfma_f32_16x16x32_bf16(aP0B[qg], ones, l_acc[qg], 0, 0, 0);
            l_acc[qg] = __builtin_amdgcn_mfma_f32_16x16x32_bf16(aP1B[qg], ones, l_acc[qg], 0, 0, 0);
        }
        #pragma unroll
        for (int dt = 0; dt < 4; dt++) {
            #pragma unroll
            for (int qg = 0; qg < 2; qg++) {
                o_acc[qg][dt] = __builtin_amdgcn_mfma_f32_16x16x32_bf16(aP0B[qg], vfB[dt * 2    ], o_acc[qg][dt], 0, 0, 0);
                o_acc[qg][dt] = __builtin_amdgcn_mfma_f32_16x16x32_bf16(aP1B[qg], vfB[dt * 2 + 1], o_acc[qg][dt], 0, 0, 0);
            }
        }
    }

    // --- epilogue: normalize, write head-concat bf16 (col l15 = d) ---
    #pragma unroll
    for (int qg = 0; qg < 2; qg++) {
        #pragma unroll
        for (int r = 0; r < 4; r++) {
            float inv = 1.0f / l_acc[qg][r];
            long row = (long)b * SQ_ + wq + qg * 16 + quad * 4 + r;
            short* Op = O + row * 1024 + h * 64 + l15;
            #pragma unroll
            for (int dt = 0; dt < 4; dt++)
                Op[dt * 16] = f2bf(o_acc[qg][dt][r] * inv);
        }
    }
}

extern "C" void kernel_launch(void* const* d_in, const int* in_sizes, int n_in,
                              void* d_out, int out_size, void* d_ws, size_t ws_size,
                              hipStream_t stream) {
    const float* x  = (const float*)d_in[0];
    const float* x2 = (const float*)d_in[1];
    const float* Wq = (const float*)d_in[2];
    const float* bq = (const float*)d_in[3];
    const float* Wk = (const float*)d_in[4];
    const float* bk = (const float*)d_in[5];
    const float* Wv = (const float*)d_in[6];
    const float* bv = (const float*)d_in[7];
    const float* Wo = (const float*)d_in[8];
    const float* bo = (const float*)d_in[9];
    float* out = (float*)d_out;

    const size_t nAct = (size_t)B_ * SK_ * DM_;    // 4,194,304
    const size_t nW   = (size_t)DM_ * DM_;         // 1,048,576
    short* bufA = (short*)d_ws;        // xb
    short* bufB = bufA + nAct;         // x2b, later O (bf16)
    short* Qb   = bufB + nAct;
    short* Kb   = Qb + nAct;
    short* VTws = Kb + nAct;           // V written directly in VT layout (sigma-permuted)
    short* WqT  = VTws + nAct;
    short* WkT  = WqT + nW;
    short* WvT  = WkT + nW;
    short* Wob  = WvT + nW;
    // total 5*nAct + 4*nW shorts = 50 MiB

    prep_kernel<<<dim3(16, 16, 6), 256, 0, stream>>>(
        Wq, Wk, Wv, Wo, x, x2, WqT, WkT, WvT, Wob, bufA, bufB);

    gemm_qkv_kernel<<<dim3(32, 8, 3), 256, 0, stream>>>(
        bufB, bufA, WqT, WkT, WvT, bq, bk, bv, Qb, Kb, VTws);

    flash_kernel<<<dim3(32, 32), 128, 0, stream>>>(Qb, Kb, VTws, bufB); // bufB = O
    gemm_out_kernel<<<dim3(64, 8), 256, 0, stream>>>(bufB, Wob, bo, out);
}

// Round 14
// 193.812 us; speedup vs baseline: 1.0060x; 1.0060x over previous
//
#include <hip/hip_runtime.h>
#include <math.h>

#define B_   2
#define SQ_  2048
#define SK_  2048
#define DM_  1024
#define H_   16
#define D_   64

typedef __attribute__((ext_vector_type(8))) short bf16x8;
typedef __attribute__((ext_vector_type(4))) float f32x4;
typedef unsigned int u32;

// fp32 -> bf16 RNE
__device__ __forceinline__ short f2bf(float f) {
    union { float f; unsigned u; } v; v.f = f;
    unsigned r = v.u + 0x7FFFu + ((v.u >> 16) & 1u);
    return (short)(r >> 16);
}
// pack two fp32 -> two bf16 (round-half-up) in one u32 — VERIFIED semantics.
__device__ __forceinline__ u32 pk2bf(float x, float y) {
    union { float f; u32 u; } a, b; a.f = x; b.f = y;
    return ((a.u + 0x8000u) >> 16) | ((b.u + 0x8000u) & 0xFFFF0000u);
}
// Bit-exact v_perm form of pk2bf (3 VALU ops).
// (inline-asm v_cvt_pk_bf16_f32 broke correctness in R2 — do not use.)
__device__ __forceinline__ u32 pkbf_rh(float x, float y) {
    union { float f; u32 u; } a, b; a.f = x; b.f = y;
    return __builtin_amdgcn_perm(b.u + 0x8000u, a.u + 0x8000u, 0x07060302u);
}

__device__ __forceinline__ void gll16(const void* g, void* l) {
    __builtin_amdgcn_global_load_lds(
        (const __attribute__((address_space(1))) u32*)g,
        (__attribute__((address_space(3))) u32*)l, 16, 0, 0);
}

// ---------------------------------------------------------------------------
// prep: z=0..2 -> Wq/Wk/Wv [16,1024,64] f32 -> WT[h*64+d][m] bf16 (transposed)
//       z=3    -> Wo fp32 -> bf16 convert
//       z=4,5  -> x / x2 fp32 -> bf16 convert
// ---------------------------------------------------------------------------
__global__ __launch_bounds__(256) void prep_kernel(
    const float* __restrict__ Wq, const float* __restrict__ Wk,
    const float* __restrict__ Wv, const float* __restrict__ Wo,
    const float* __restrict__ x,  const float* __restrict__ x2,
    short* __restrict__ WqT, short* __restrict__ WkT,
    short* __restrict__ WvT, short* __restrict__ Wob,
    short* __restrict__ xb,  short* __restrict__ x2b)
{
    const int t = threadIdx.x;
    const int z = blockIdx.z;
    if (z >= 3) {
        const float* src = (z == 3) ? Wo : (z == 4) ? x : x2;
        short* dst       = (z == 3) ? Wob : (z == 4) ? xb : x2b;
        int nloop = (z == 3) ? 4 : 16;              // Wo: 1M floats; x: 4M
        int bid = blockIdx.y * 16 + blockIdx.x;     // 0..255
        #pragma unroll 4
        for (int j = 0; j < nloop; j++) {
            int i = bid * (nloop * 256) + j * 256 + t;   // float4 units
            float4 v = ((const float4*)src)[i];
            short4 s;
            s.x = f2bf(v.x); s.y = f2bf(v.y); s.z = f2bf(v.z); s.w = f2bf(v.w);
            ((short4*)dst)[i] = s;
        }
        return;
    }
    const float* W = (z == 0) ? Wq : (z == 1) ? Wk : Wv;
    short* WT      = (z == 0) ? WqT : (z == 1) ? WkT : WvT;
    const int h  = blockIdx.y;
    const int m0 = blockIdx.x * 64;
    __shared__ short Ls[64][68];

    #pragma unroll
    for (int it = 0; it < 4; it++) {
        int lin = it * 256 + t;         // float4 units, 1024 total
        int m = lin >> 4, d4 = lin & 15;
        float4 v = *(const float4*)&W[((long)h * DM_ + m0 + m) * D_ + d4 * 4];
        short4 s;
        s.x = f2bf(v.x); s.y = f2bf(v.y); s.z = f2bf(v.z); s.w = f2bf(v.w);
        *(short4*)&Ls[m][d4 * 4] = s;
    }
    __syncthreads();
    #pragma unroll
    for (int it = 0; it < 2; it++) {
        int d = (t >> 3) + it * 32, scol = t & 7;
        bf16x8 vv;
        #pragma unroll
        for (int j = 0; j < 8; j++) vv[j] = Ls[scol * 8 + j][d];
        *(bf16x8*)&WT[((long)h * 64 + d) * DM_ + m0 + scol * 8] = vv;
    }
}

// ---------------------------------------------------------------------------
// bf16 MFMA GEMM core, 128x128 tile, BK=64, gll16 + XOR swizzle,
// double-buffered LDS + one barrier per K-step (R9 verified).
// Epilogue: DIRECT global stores (R9) — R11's LDS round-trip regressed 6 us.
// NOTE (R8 lesson): do NOT XCD-swizzle this grid.
// NOTE (R12 lesson): kh-rotation (flash-style deferred tail) is neutral-to-
// negative here — keep the plain 2-phase loop.
// ---------------------------------------------------------------------------
__device__ __forceinline__ void gemm_stage(
    short* __restrict__ Asb, short* __restrict__ Bsb,
    const short* __restrict__ A, const short* __restrict__ Bw,
    int r0, int n0, int k0c, int w, int srow, int sc)
{
    #pragma unroll
    for (int j = 0; j < 4; j++) {
        int q   = w * 4 + j;
        int row = q * 8 + srow;
        gll16(A  + ((long)(r0 + row) << 10) + k0c + sc * 8, Asb + q * 512);
        gll16(Bw + ((long)(n0 + row) << 10) + k0c + sc * 8, Bsb + q * 512);
    }
}

template <int MODE>
__device__ __forceinline__ void gemm_core(
    short* __restrict__ Ls,
    const short* __restrict__ A, const short* __restrict__ Bw,
    const float* __restrict__ bias, void* __restrict__ outp,
    int r0, int n0, float oscale)
{
    const int t    = threadIdx.x;
    const int w    = t >> 6;
    const int ln   = t & 63;
    const int l15  = ln & 15;
    const int quad = ln >> 4;
    const int wr   = w >> 1;
    const int wc   = w & 1;

    f32x4 acc[4][4];
    #pragma unroll
    for (int i = 0; i < 4; i++)
        #pragma unroll
        for (int j = 0; j < 4; j++) acc[i][j] = (f32x4){0.f, 0.f, 0.f, 0.f};

    const int srow = ln >> 3;
    const int sc   = (ln & 7) ^ srow;
    const int rsw  = l15 & 7;

    // prologue: stage k0=0 into buffer 0
    gemm_stage(Ls, Ls + 8192, A, Bw, r0, n0, 0, w, srow, sc);

    int cur = 0;
    for (int k0 = 0; k0 < 1024; k0 += 64) {
        __syncthreads();            // buf[cur] staged; prev reads drained
        if (k0 + 64 < 1024) {
            short* Anx = Ls + (cur ^ 1) * 16384;
            gemm_stage(Anx, Anx + 8192, A, Bw, r0, n0, k0 + 64, w, srow, sc);
        }
        const short* Asb = Ls + cur * 16384;
        const short* Bsb = Asb + 8192;
        #pragma unroll
        for (int kh = 0; kh < 2; kh++) {
            bf16x8 af[4], bfr[4];
            #pragma unroll
            for (int i = 0; i < 4; i++) {
                int ra = wr * 64 + i * 16 + l15;
                int rb = wc * 64 + i * 16 + l15;
                int pc = ((kh * 4 + quad) ^ rsw) * 8;
                af[i]  = *(const bf16x8*)&Asb[ra * 64 + pc];
                bfr[i] = *(const bf16x8*)&Bsb[rb * 64 + pc];
            }
            #pragma unroll
            for (int i = 0; i < 4; i++)
                #pragma unroll
                for (int j = 0; j < 4; j++)
                    acc[i][j] = __builtin_amdgcn_mfma_f32_16x16x32_bf16(
                        af[i], bfr[j], acc[i][j], 0, 0, 0);
        }
        cur ^= 1;
    }

    #pragma unroll
    for (int j = 0; j < 4; j++) {
        int col = n0 + wc * 64 + j * 16 + l15;
        float bv = bias[col];
        if (MODE == 2) {
            // VT[((b*16+h)*64 + d)][sp], 4 consecutive s per lane (short4).
            // sp = tile-local sigma^{-1}(s): bits (5,4,3,2,1,0) <- (s5,s3,s2,s4,s1,s0)
            int hh = col >> 6, dd = col & 63;
            #pragma unroll
            for (int i = 0; i < 4; i++) {
                int rowb = r0 + wr * 64 + i * 16 + quad * 4;
                int bb = rowb >> 11, ss = rowb & 2047;
                int sl = ss & 63;
                int sp = (ss & ~63) | (sl & 35) | ((sl & 12) << 1) | ((sl & 16) >> 2);
                short4 sv;
                sv.x = f2bf(acc[i][j][0] + bv);
                sv.y = f2bf(acc[i][j][1] + bv);
                sv.z = f2bf(acc[i][j][2] + bv);
                sv.w = f2bf(acc[i][j][3] + bv);
                *(short4*)&((short*)outp)[
                    ((long)(((bb << 4) + hh) * 64 + dd) << 11) + sp] = sv;
            }
        } else {
            #pragma unroll
            for (int i = 0; i < 4; i++) {
                int rowb = r0 + wr * 64 + i * 16 + quad * 4;
                #pragma unroll
                for (int r = 0; r < 4; r++) {
                    float v = (acc[i][j][r] + bv) * oscale;
                    if (MODE == 0)
                        ((short*)outp)[(long)(rowb + r) * 1024 + col] = f2bf(v);
                    else
                        ((float*)outp)[(long)(rowb + r) * 1024 + col] = v;
                }
            }
        }
    }
}

// Q scale: 1/sqrt(64) * log2(e)  (flash uses raw v_exp_f32 = 2^x)
#define QSCALE 0.180336880977f

__global__ __launch_bounds__(256) void gemm_qkv_kernel(
    const short* __restrict__ x2b, const short* __restrict__ xb,
    const short* __restrict__ WqT, const short* __restrict__ WkT,
    const short* __restrict__ WvT,
    const float* __restrict__ bq, const float* __restrict__ bk,
    const float* __restrict__ bv,
    short* __restrict__ Qb, short* __restrict__ Kb, short* __restrict__ VT)
{
    __shared__ short Ls[2 * 16384];     // 64 KB, shared by all MODE branches
    const int z = blockIdx.z;
    if (z == 0) {
        gemm_core<0>(Ls, x2b, WqT, bq, Qb, blockIdx.x * 128, blockIdx.y * 128, QSCALE);
    } else if (z == 1) {
        gemm_core<0>(Ls, xb, WkT, bk, Kb, blockIdx.x * 128, blockIdx.y * 128, 1.0f);
    } else {
        gemm_core<2>(Ls, xb, WvT, bv, VT, blockIdx.x * 128, blockIdx.y * 128, 1.0f);
    }
}

// ---------------------------------------------------------------------------
// gemm_out (R14): 64x64 tiles -> grid (64,16) = 1024 blocks = 4 blocks/CU,
// 32 KB LDS. Same verified double-buffer one-barrier-per-K-step schedule.
// Rationale: at 64x128/2-per-CU this kernel ran ~3x below gemm_qkv's
// FLOP rate; 4-way block overlap per CU covers the barrier drains.
// 4 waves in 2x2; per wave 32x32 output (acc 2x2).
// ---------------------------------------------------------------------------
__device__ __forceinline__ void gout_stage(
    short* __restrict__ Asb, short* __restrict__ Bsb,
    const short* __restrict__ A, const short* __restrict__ Bw,
    int r0, int n0, int k0c, int w, int srow, int sc)
{
    #pragma unroll
    for (int j = 0; j < 4; j++) {           // 16 issues: 8 A + 8 B
        int q = w * 4 + j;
        if (q < 8) {
            int row = q * 8 + srow;
            gll16(A + ((long)(r0 + row) << 10) + k0c + sc * 8, Asb + q * 512);
        } else {
            int qb = q - 8;
            int row = qb * 8 + srow;
            gll16(Bw + ((long)(n0 + row) << 10) + k0c + sc * 8, Bsb + qb * 512);
        }
    }
}

__global__ __launch_bounds__(256) void gemm_out_kernel(
    const short* __restrict__ A, const short* __restrict__ Bw,
    const float* __restrict__ bias, float* __restrict__ outp)
{
    __shared__ short Ls[2 * 8192];      // 32 KB: buf b -> As = b*8192, Bs = +4096

    const int r0   = blockIdx.x * 64;
    const int n0   = blockIdx.y * 64;
    const int t    = threadIdx.x;
    const int w    = t >> 6;
    const int ln   = t & 63;
    const int l15  = ln & 15;
    const int quad = ln >> 4;
    const int wr   = w >> 1;            // row group (32 rows)
    const int wc   = w & 1;             // col group (32 cols)

    f32x4 acc[2][2];
    #pragma unroll
    for (int i = 0; i < 2; i++)
        #pragma unroll
        for (int j = 0; j < 2; j++) acc[i][j] = (f32x4){0.f, 0.f, 0.f, 0.f};

    const int srow = ln >> 3;
    const int sc   = (ln & 7) ^ srow;
    const int rsw  = l15 & 7;

    gout_stage(Ls, Ls + 4096, A, Bw, r0, n0, 0, w, srow, sc);

    int cur = 0;
    for (int k0 = 0; k0 < 1024; k0 += 64) {
        __syncthreads();
        if (k0 + 64 < 1024) {
            short* Anx = Ls + (cur ^ 1) * 8192;
            gout_stage(Anx, Anx + 4096, A, Bw, r0, n0, k0 + 64, w, srow, sc);
        }
        const short* Asb = Ls + cur * 8192;
        const short* Bsb = Asb + 4096;
        #pragma unroll
        for (int kh = 0; kh < 2; kh++) {
            int pc = ((kh * 4 + quad) ^ rsw) * 8;
            bf16x8 af[2], bfr[2];
            #pragma unroll
            for (int i = 0; i < 2; i++)
                af[i] = *(const bf16x8*)&Asb[(wr * 32 + i * 16 + l15) * 64 + pc];
            #pragma unroll
            for (int j = 0; j < 2; j++)
                bfr[j] = *(const bf16x8*)&Bsb[(wc * 32 + j * 16 + l15) * 64 + pc];
            #pragma unroll
            for (int i = 0; i < 2; i++)
                #pragma unroll
                for (int j = 0; j < 2; j++)
                    acc[i][j] = __builtin_amdgcn_mfma_f32_16x16x32_bf16(
                        af[i], bfr[j], acc[i][j], 0, 0, 0);
        }
        cur ^= 1;
    }

    #pragma unroll
    for (int j = 0; j < 2; j++) {
        int col = n0 + wc * 32 + j * 16 + l15;
        float bv = bias[col];
        #pragma unroll
        for (int i = 0; i < 2; i++) {
            int rowb = r0 + wr * 32 + i * 16 + quad * 4;
            #pragma unroll
            for (int r = 0; r < 4; r++)
                outp[(long)(rowb + r) * 1024 + col] = acc[i][j][r] + bv;
        }
    }
}

// ---------------------------------------------------------------------------
// MFMA flash attention (R9 verified config — 45.8 us, RESTORED):
// 32 q rows/wave (2 q-groups), 256-thread 4-wave blocks, KVBLK=128,
// register-prefetch pipeline + rotated P5 + XCD swizzle.
// R10 lesson: 64 q/wave (1 wave/SIMD) regressed to 57.6.
// R13 lesson: 2-wave blocks + KVBLK=64 regressed to 56.5 (barrier freq
// doubled, pipeline too shallow). THIS is the converged structure.
// ---------------------------------------------------------------------------
__global__ __launch_bounds__(256, 2) void flash_kernel(
    const short* __restrict__ Q, const short* __restrict__ K,
    const short* __restrict__ VT, short* __restrict__ O)
{
    const int t    = threadIdx.x;
    const int wave = t >> 6;
    const int ln   = t & 63;
    const int l15  = ln & 15;
    const int quad = ln >> 4;
    // XCD swizzle (bijective, 512 % 8 == 0): 64 consecutive work-ids
    // (= 4 complete bh) per XCD -> 2 MB K/V in the 4 MB XCD L2.
    const int f   = blockIdx.x + (blockIdx.y << 4);
    const int wid = ((f & 7) << 6) | (f >> 3);
    const int bh  = wid >> 4;
    const int b   = bh >> 4;
    const int h   = bh & 15;
    const int q0  = (wid & 15) * 128;
    const int wq  = q0 + wave * 32;         // this wave's first q row

    __shared__ short Ks[2][2][64 * 64];     // [buf][half][kpos][d]
    __shared__ short Vs[2][2][64 * 64];     // [buf][half][d][kpos(sigma)]

    const int srow = ln >> 3;               // row within 8-row staging chunk
    const int sc   = (ln & 7) ^ srow;       // swizzled source chunk (16B)
    const int rsw  = l15 & 7;               // read-side swizzle key
    const int pc0  = ((quad    ) ^ rsw) * 8;
    const int pc1  = ((quad + 4) ^ rsw) * 8;
    const int rb   = l15 * 64;              // fragment row base

    // Q B-frags (pre-scaled by 0.125*log2e): 2 q-groups
    bf16x8 aQ0[2], aQ1[2];
    #pragma unroll
    for (int qg = 0; qg < 2; qg++) {
        const short* Qp = Q + ((long)(b * SQ_ + wq + qg * 16 + l15)) * 1024
                            + h * 64 + quad * 8;
        aQ0[qg] = *(const bf16x8*)(Qp);
        aQ1[qg] = *(const bf16x8*)(Qp + 32);
    }

    bf16x8 ones;
    #pragma unroll
    for (int j = 0; j < 8; j++) ones[j] = (short)0x3F80;   // bf16 1.0

    const f32x4 fz = (f32x4){0.f, 0.f, 0.f, 0.f};   // shared zero C-in

    f32x4 o_acc[2][4];
    f32x4 l_acc[2];
    #pragma unroll
    for (int qg = 0; qg < 2; qg++) {
        l_acc[qg] = fz;
        #pragma unroll
        for (int i = 0; i < 4; i++) o_acc[qg][i] = fz;
    }

    const short* Kbase = K  + ((long)b * SK_) * 1024 + h * 64;
    const short* Vbase = VT + (long)bh * D_ * SK_;
    const int qqa = wave * 2, qqb = wave * 2 + 1;
    const int rowa = qqa * 8 + srow, rowb_ = qqb * 8 + srow;

    // stage one 64-k half-tile into (buf, half)
    #define STAGE(bufp, half, kbase)                                            \
        gll16(Kbase + (long)((kbase) + rowa)  * 1024 + sc * 8,                  \
              &Ks[bufp][half][qqa * 512]);                                      \
        gll16(Kbase + (long)((kbase) + rowb_) * 1024 + sc * 8,                  \
              &Ks[bufp][half][qqb * 512]);                                      \
        gll16(Vbase + (long)rowa  * 2048 + (kbase) + sc * 8,                    \
              &Vs[bufp][half][qqa * 512]);                                      \
        gll16(Vbase + (long)rowb_ * 2048 + (kbase) + sc * 8,                    \
              &Vs[bufp][half][qqb * 512]);

    // prologue: stage k-tile pair 0 into buffer 0
    STAGE(0, 0, 0)
    STAGE(0, 1, 64)

    // loop-carried deferred-P5 state (written in P4, consumed next iter)
    u32 pwB[2][8];
    bf16x8 vfB[8];

    int cur = 0;
    for (int k0 = 0; k0 < SK_; k0 += 128) {
        __syncthreads();
        if (k0 + 128 < SK_) {
            int nx = cur ^ 1;
            STAGE(nx, 0, k0 + 128)
            STAGE(nx, 1, k0 + 192)
        }
        const short* K0 = &Ks[cur][0][0];
        const short* K1 = &Ks[cur][1][0];
        const short* V0 = &Vs[cur][0][0];
        const short* V1 = &Vs[cur][1][0];

        // ---- P0: issue K0 fragment reads ----
        bf16x8 kfA[8];
        #pragma unroll
        for (int kt = 0; kt < 4; kt++) {
            const short* kr = &K0[kt * 1024 + rb];
            kfA[kt * 2    ] = *(const bf16x8*)&kr[pc0];
            kfA[kt * 2 + 1] = *(const bf16x8*)&kr[pc1];
        }

        // ---- P5 of PREVIOUS iteration (registers only): hides K0 reads ----
        if (k0) {
            bf16x8 aP0B[2], aP1B[2];
            #pragma unroll
            for (int qg = 0; qg < 2; qg++) {
                union { bf16x8 v; u32 w[4]; } u0, u1;
                u0.w[0] = pwB[qg][0]; u0.w[1] = pwB[qg][1];
                u0.w[2] = pwB[qg][2]; u0.w[3] = pwB[qg][3];
                u1.w[0] = pwB[qg][4]; u1.w[1] = pwB[qg][5];
                u1.w[2] = pwB[qg][6]; u1.w[3] = pwB[qg][7];
                aP0B[qg] = u0.v; aP1B[qg] = u1.v;
            }
            __builtin_amdgcn_s_setprio(1);
            #pragma unroll
            for (int qg = 0; qg < 2; qg++) {
                l_acc[qg] = __builtin_amdgcn_mfma_f32_16x16x32_bf16(aP0B[qg], ones, l_acc[qg], 0, 0, 0);
                l_acc[qg] = __builtin_amdgcn_mfma_f32_16x16x32_bf16(aP1B[qg], ones, l_acc[qg], 0, 0, 0);
            }
            #pragma unroll
            for (int dt = 0; dt < 4; dt++) {
                #pragma unroll
                for (int qg = 0; qg < 2; qg++) {
                    o_acc[qg][dt] = __builtin_amdgcn_mfma_f32_16x16x32_bf16(aP0B[qg], vfB[dt * 2    ], o_acc[qg][dt], 0, 0, 0);
                    o_acc[qg][dt] = __builtin_amdgcn_mfma_f32_16x16x32_bf16(aP1B[qg], vfB[dt * 2 + 1], o_acc[qg][dt], 0, 0, 0);
                }
            }
            __builtin_amdgcn_s_setprio(0);
        }

        // ---- P1: issue K1 reads; QK half0 off kfA ----
        bf16x8 kfB[8];
        #pragma unroll
        for (int kt = 0; kt < 4; kt++) {
            const short* kr = &K1[kt * 1024 + rb];
            kfB[kt * 2    ] = *(const bf16x8*)&kr[pc0];
            kfB[kt * 2 + 1] = *(const bf16x8*)&kr[pc1];
        }
        f32x4 zA[2][4], zB[2][4];
        #pragma unroll
        for (int kt = 0; kt < 4; kt++)
            #pragma unroll
            for (int qg = 0; qg < 2; qg++) {
                f32x4 z = __builtin_amdgcn_mfma_f32_16x16x32_bf16(kfA[kt * 2], aQ0[qg], fz, 0, 0, 0);
                zA[qg][kt] = __builtin_amdgcn_mfma_f32_16x16x32_bf16(kfA[kt * 2 + 1], aQ1[qg], z, 0, 0, 0);
            }

        // ---- P2: issue V0 reads; QK half1 (kfB) ∥ exp2+pack half0 ----
        bf16x8 vfA[8];
        #pragma unroll
        for (int dt = 0; dt < 4; dt++) {
            const short* vr = &V0[dt * 1024 + rb];
            vfA[dt * 2    ] = *(const bf16x8*)&vr[pc0];
            vfA[dt * 2 + 1] = *(const bf16x8*)&vr[pc1];
        }
        u32 pwA[2][8];
        #pragma unroll
        for (int kt = 0; kt < 4; kt++) {
            #pragma unroll
            for (int qg = 0; qg < 2; qg++) {
                f32x4 z = __builtin_amdgcn_mfma_f32_16x16x32_bf16(kfB[kt * 2], aQ0[qg], fz, 0, 0, 0);
                zB[qg][kt] = __builtin_amdgcn_mfma_f32_16x16x32_bf16(kfB[kt * 2 + 1], aQ1[qg], z, 0, 0, 0);
            }
            #pragma unroll
            for (int qg = 0; qg < 2; qg++) {
                f32x4 s = zA[qg][kt];
                pwA[qg][kt * 2    ] = pkbf_rh(__builtin_amdgcn_exp2f(s[0]),
                                              __builtin_amdgcn_exp2f(s[1]));
                pwA[qg][kt * 2 + 1] = pkbf_rh(__builtin_amdgcn_exp2f(s[2]),
                                              __builtin_amdgcn_exp2f(s[3]));
            }
        }

        // ---- P3: aP(half0) + l(half0) ----
        bf16x8 aP0A[2], aP1A[2];
        #pragma unroll
        for (int qg = 0; qg < 2; qg++) {
            union { bf16x8 v; u32 w[4]; } u0, u1;
            u0.w[0] = pwA[qg][0]; u0.w[1] = pwA[qg][1];
            u0.w[2] = pwA[qg][2]; u0.w[3] = pwA[qg][3];
            u1.w[0] = pwA[qg][4]; u1.w[1] = pwA[qg][5];
            u1.w[2] = pwA[qg][6]; u1.w[3] = pwA[qg][7];
            aP0A[qg] = u0.v; aP1A[qg] = u1.v;
            l_acc[qg] = __builtin_amdgcn_mfma_f32_16x16x32_bf16(aP0A[qg], ones, l_acc[qg], 0, 0, 0);
            l_acc[qg] = __builtin_amdgcn_mfma_f32_16x16x32_bf16(aP1A[qg], ones, l_acc[qg], 0, 0, 0);
        }

        // ---- P4: issue V1 reads; PV half0 (vfA) ∥ exp2+pack half1 -> pwB ----
        #pragma unroll
        for (int dt = 0; dt < 4; dt++) {
            const short* vr = &V1[dt * 1024 + rb];
            vfB[dt * 2    ] = *(const bf16x8*)&vr[pc0];
            vfB[dt * 2 + 1] = *(const bf16x8*)&vr[pc1];
        }
        #pragma unroll
        for (int dt = 0; dt < 4; dt++) {
            #pragma unroll
            for (int qg = 0; qg < 2; qg++) {
                o_acc[qg][dt] = __builtin_amdgcn_mfma_f32_16x16x32_bf16(aP0A[qg], vfA[dt * 2    ], o_acc[qg][dt], 0, 0, 0);
                o_acc[qg][dt] = __builtin_amdgcn_mfma_f32_16x16x32_bf16(aP1A[qg], vfA[dt * 2 + 1], o_acc[qg][dt], 0, 0, 0);
            }
            #pragma unroll
            for (int qg = 0; qg < 2; qg++) {
                f32x4 s = zB[qg][dt];
                pwB[qg][dt * 2    ] = pkbf_rh(__builtin_amdgcn_exp2f(s[0]),
                                              __builtin_amdgcn_exp2f(s[1]));
                pwB[qg][dt * 2 + 1] = pkbf_rh(__builtin_amdgcn_exp2f(s[2]),
                                              __builtin_amdgcn_exp2f(s[3]));
            }
        }
        cur ^= 1;
    }
    #undef STAGE

    // ---- final deferred P5 ----
    {
        bf16x8 aP0B[2], aP1B[2];
        #pragma unroll
        for (int qg = 0; qg < 2; qg++) {
            union { bf16x8 v; u32 w[4]; } u0, u1;
            u0.w[0] = pwB[qg][0]; u0.w[1] = pwB[qg][1];
            u0.w[2] = pwB[qg][2]; u0.w[3] = pwB[qg][3];
            u1.w[0] = pwB[qg][4]; u1.w[1] = pwB[qg][5];
            u1.w[2] = pwB[qg][6]; u1.w[3] = pwB[qg][7];
            aP0B[qg] = u0.v; aP1B[qg] = u1.v;
            l_acc[qg] = __builtin_amdgcn_mfma_f32_16x16x32_bf16(aP0B[qg], ones, l_acc[qg], 0, 0, 0);
            l_acc[qg] = __builtin_amdgcn_mfma_f32_16x16x32_bf16(aP1B[qg], ones, l_acc[qg], 0, 0, 0);
        }
        #pragma unroll
        for (int dt = 0; dt < 4; dt++) {
            #pragma unroll
            for (int qg = 0; qg < 2; qg++) {
                o_acc[qg][dt] = __builtin_amdgcn_mfma_f32_16x16x32_bf16(aP0B[qg], vfB[dt * 2    ], o_acc[qg][dt], 0, 0, 0);
                o_acc[qg][dt] = __builtin_amdgcn_mfma_f32_16x16x32_bf16(aP1B[qg], vfB[dt * 2 + 1], o_acc[qg][dt], 0, 0, 0);
            }
        }
    }

    // --- epilogue: normalize, write head-concat bf16 (col l15 = d) ---
    #pragma unroll
    for (int qg = 0; qg < 2; qg++) {
        #pragma unroll
        for (int r = 0; r < 4; r++) {
            float inv = 1.0f / l_acc[qg][r];
            long row = (long)b * SQ_ + wq + qg * 16 + quad * 4 + r;
            short* Op = O + row * 1024 + h * 64 + l15;
            #pragma unroll
            for (int dt = 0; dt < 4; dt++)
                Op[dt * 16] = f2bf(o_acc[qg][dt][r] * inv);
        }
    }
}

extern "C" void kernel_launch(void* const* d_in, const int* in_sizes, int n_in,
                              void* d_out, int out_size, void* d_ws, size_t ws_size,
                              hipStream_t stream) {
    const float* x  = (const float*)d_in[0];
    const float* x2 = (const float*)d_in[1];
    const float* Wq = (const float*)d_in[2];
    const float* bq = (const float*)d_in[3];
    const float* Wk = (const float*)d_in[4];
    const float* bk = (const float*)d_in[5];
    const float* Wv = (const float*)d_in[6];
    const float* bv = (const float*)d_in[7];
    const float* Wo = (const float*)d_in[8];
    const float* bo = (const float*)d_in[9];
    float* out = (float*)d_out;

    const size_t nAct = (size_t)B_ * SK_ * DM_;    // 4,194,304
    const size_t nW   = (size_t)DM_ * DM_;         // 1,048,576
    short* bufA = (short*)d_ws;        // xb
    short* bufB = bufA + nAct;         // x2b, later O (bf16)
    short* Qb   = bufB + nAct;
    short* Kb   = Qb + nAct;
    short* VTws = Kb + nAct;           // V written directly in VT layout (sigma-permuted)
    short* WqT  = VTws + nAct;
    short* WkT  = WqT + nW;
    short* WvT  = WkT + nW;
    short* Wob  = WvT + nW;
    // total 5*nAct + 4*nW shorts = 50 MiB

    prep_kernel<<<dim3(16, 16, 6), 256, 0, stream>>>(
        Wq, Wk, Wv, Wo, x, x2, WqT, WkT, WvT, Wob, bufA, bufB);

    gemm_qkv_kernel<<<dim3(32, 8, 3), 256, 0, stream>>>(
        bufB, bufA, WqT, WkT, WvT, bq, bk, bv, Qb, Kb, VTws);

    flash_kernel<<<dim3(16, 32), 256, 0, stream>>>(Qb, Kb, VTws, bufB); // bufB = O
    gemm_out_kernel<<<dim3(64, 16), 256, 0, stream>>>(bufB, Wob, bo, out);
}

// Round 15
// 190.230 us; speedup vs baseline: 1.0250x; 1.0188x over previous
//
#include <hip/hip_runtime.h>
#include <math.h>

#define B_   2
#define SQ_  2048
#define SK_  2048
#define DM_  1024
#define H_   16
#define D_   64

typedef __attribute__((ext_vector_type(8))) short bf16x8;
typedef __attribute__((ext_vector_type(4))) float f32x4;
typedef unsigned int u32;

// fp32 -> bf16 RNE
__device__ __forceinline__ short f2bf(float f) {
    union { float f; unsigned u; } v; v.f = f;
    unsigned r = v.u + 0x7FFFu + ((v.u >> 16) & 1u);
    return (short)(r >> 16);
}
// pack two fp32 -> two bf16 (round-half-up) in one u32 — VERIFIED semantics.
__device__ __forceinline__ u32 pk2bf(float x, float y) {
    union { float f; u32 u; } a, b; a.f = x; b.f = y;
    return ((a.u + 0x8000u) >> 16) | ((b.u + 0x8000u) & 0xFFFF0000u);
}
// Bit-exact v_perm form of pk2bf (3 VALU ops).
// (inline-asm v_cvt_pk_bf16_f32 broke correctness in R2 — do not use.)
__device__ __forceinline__ u32 pkbf_rh(float x, float y) {
    union { float f; u32 u; } a, b; a.f = x; b.f = y;
    return __builtin_amdgcn_perm(b.u + 0x8000u, a.u + 0x8000u, 0x07060302u);
}

__device__ __forceinline__ void gll16(const void* g, void* l) {
    __builtin_amdgcn_global_load_lds(
        (const __attribute__((address_space(1))) u32*)g,
        (__attribute__((address_space(3))) u32*)l, 16, 0, 0);
}

// ---------------------------------------------------------------------------
// prep: z=0..2 -> Wq/Wk/Wv [16,1024,64] f32 -> WT[h*64+d][m] bf16 (transposed)
//       z=3    -> Wo fp32 -> bf16 convert
//       z=4,5  -> x / x2 fp32 -> bf16 convert
// ---------------------------------------------------------------------------
__global__ __launch_bounds__(256) void prep_kernel(
    const float* __restrict__ Wq, const float* __restrict__ Wk,
    const float* __restrict__ Wv, const float* __restrict__ Wo,
    const float* __restrict__ x,  const float* __restrict__ x2,
    short* __restrict__ WqT, short* __restrict__ WkT,
    short* __restrict__ WvT, short* __restrict__ Wob,
    short* __restrict__ xb,  short* __restrict__ x2b)
{
    const int t = threadIdx.x;
    const int z = blockIdx.z;
    if (z >= 3) {
        const float* src = (z == 3) ? Wo : (z == 4) ? x : x2;
        short* dst       = (z == 3) ? Wob : (z == 4) ? xb : x2b;
        int nloop = (z == 3) ? 4 : 16;              // Wo: 1M floats; x: 4M
        int bid = blockIdx.y * 16 + blockIdx.x;     // 0..255
        #pragma unroll 4
        for (int j = 0; j < nloop; j++) {
            int i = bid * (nloop * 256) + j * 256 + t;   // float4 units
            float4 v = ((const float4*)src)[i];
            short4 s;
            s.x = f2bf(v.x); s.y = f2bf(v.y); s.z = f2bf(v.z); s.w = f2bf(v.w);
            ((short4*)dst)[i] = s;
        }
        return;
    }
    const float* W = (z == 0) ? Wq : (z == 1) ? Wk : Wv;
    short* WT      = (z == 0) ? WqT : (z == 1) ? WkT : WvT;
    const int h  = blockIdx.y;
    const int m0 = blockIdx.x * 64;
    __shared__ short Ls[64][68];

    #pragma unroll
    for (int it = 0; it < 4; it++) {
        int lin = it * 256 + t;         // float4 units, 1024 total
        int m = lin >> 4, d4 = lin & 15;
        float4 v = *(const float4*)&W[((long)h * DM_ + m0 + m) * D_ + d4 * 4];
        short4 s;
        s.x = f2bf(v.x); s.y = f2bf(v.y); s.z = f2bf(v.z); s.w = f2bf(v.w);
        *(short4*)&Ls[m][d4 * 4] = s;
    }
    __syncthreads();
    #pragma unroll
    for (int it = 0; it < 2; it++) {
        int d = (t >> 3) + it * 32, scol = t & 7;
        bf16x8 vv;
        #pragma unroll
        for (int j = 0; j < 8; j++) vv[j] = Ls[scol * 8 + j][d];
        *(bf16x8*)&WT[((long)h * 64 + d) * DM_ + m0 + scol * 8] = vv;
    }
}

// ---------------------------------------------------------------------------
// bf16 MFMA GEMM core, 128x128 tile, BK=64, gll16 + XOR swizzle,
// double-buffered LDS + one barrier per K-step (R9 verified).
// Epilogue: DIRECT global stores (R9) — R11's LDS round-trip regressed 6 us.
// Lessons locked in: no XCD swizzle here (R8, -24us); no kh-rotation (R12);
// 128x128 is the right tile (R14: 64x64 gemm_out regressed).
// ---------------------------------------------------------------------------
__device__ __forceinline__ void gemm_stage(
    short* __restrict__ Asb, short* __restrict__ Bsb,
    const short* __restrict__ A, const short* __restrict__ Bw,
    int r0, int n0, int k0c, int w, int srow, int sc)
{
    #pragma unroll
    for (int j = 0; j < 4; j++) {
        int q   = w * 4 + j;
        int row = q * 8 + srow;
        gll16(A  + ((long)(r0 + row) << 10) + k0c + sc * 8, Asb + q * 512);
        gll16(Bw + ((long)(n0 + row) << 10) + k0c + sc * 8, Bsb + q * 512);
    }
}

template <int MODE>
__device__ __forceinline__ void gemm_core(
    short* __restrict__ Ls,
    const short* __restrict__ A, const short* __restrict__ Bw,
    const float* __restrict__ bias, void* __restrict__ outp,
    int r0, int n0, float oscale)
{
    const int t    = threadIdx.x;
    const int w    = t >> 6;
    const int ln   = t & 63;
    const int l15  = ln & 15;
    const int quad = ln >> 4;
    const int wr   = w >> 1;
    const int wc   = w & 1;

    f32x4 acc[4][4];
    #pragma unroll
    for (int i = 0; i < 4; i++)
        #pragma unroll
        for (int j = 0; j < 4; j++) acc[i][j] = (f32x4){0.f, 0.f, 0.f, 0.f};

    const int srow = ln >> 3;
    const int sc   = (ln & 7) ^ srow;
    const int rsw  = l15 & 7;

    // prologue: stage k0=0 into buffer 0
    gemm_stage(Ls, Ls + 8192, A, Bw, r0, n0, 0, w, srow, sc);

    int cur = 0;
    for (int k0 = 0; k0 < 1024; k0 += 64) {
        __syncthreads();            // buf[cur] staged; prev reads drained
        if (k0 + 64 < 1024) {
            short* Anx = Ls + (cur ^ 1) * 16384;
            gemm_stage(Anx, Anx + 8192, A, Bw, r0, n0, k0 + 64, w, srow, sc);
        }
        const short* Asb = Ls + cur * 16384;
        const short* Bsb = Asb + 8192;
        #pragma unroll
        for (int kh = 0; kh < 2; kh++) {
            bf16x8 af[4], bfr[4];
            #pragma unroll
            for (int i = 0; i < 4; i++) {
                int ra = wr * 64 + i * 16 + l15;
                int rb = wc * 64 + i * 16 + l15;
                int pc = ((kh * 4 + quad) ^ rsw) * 8;
                af[i]  = *(const bf16x8*)&Asb[ra * 64 + pc];
                bfr[i] = *(const bf16x8*)&Bsb[rb * 64 + pc];
            }
            #pragma unroll
            for (int i = 0; i < 4; i++)
                #pragma unroll
                for (int j = 0; j < 4; j++)
                    acc[i][j] = __builtin_amdgcn_mfma_f32_16x16x32_bf16(
                        af[i], bfr[j], acc[i][j], 0, 0, 0);
        }
        cur ^= 1;
    }

    #pragma unroll
    for (int j = 0; j < 4; j++) {
        int col = n0 + wc * 64 + j * 16 + l15;
        float bv = bias[col];
        if (MODE == 2) {
            // VT[((b*16+h)*64 + d)][sp], 4 consecutive s per lane (short4).
            // sp = tile-local sigma^{-1}(s): bits (5,4,3,2,1,0) <- (s5,s3,s2,s4,s1,s0)
            int hh = col >> 6, dd = col & 63;
            #pragma unroll
            for (int i = 0; i < 4; i++) {
                int rowb = r0 + wr * 64 + i * 16 + quad * 4;
                int bb = rowb >> 11, ss = rowb & 2047;
                int sl = ss & 63;
                int sp = (ss & ~63) | (sl & 35) | ((sl & 12) << 1) | ((sl & 16) >> 2);
                short4 sv;
                sv.x = f2bf(acc[i][j][0] + bv);
                sv.y = f2bf(acc[i][j][1] + bv);
                sv.z = f2bf(acc[i][j][2] + bv);
                sv.w = f2bf(acc[i][j][3] + bv);
                *(short4*)&((short*)outp)[
                    ((long)(((bb << 4) + hh) * 64 + dd) << 11) + sp] = sv;
            }
        } else {
            #pragma unroll
            for (int i = 0; i < 4; i++) {
                int rowb = r0 + wr * 64 + i * 16 + quad * 4;
                #pragma unroll
                for (int r = 0; r < 4; r++) {
                    float v = (acc[i][j][r] + bv) * oscale;
                    if (MODE == 0)
                        ((short*)outp)[(long)(rowb + r) * 1024 + col] = f2bf(v);
                    else
                        ((float*)outp)[(long)(rowb + r) * 1024 + col] = v;
                }
            }
        }
    }
}

// Q scale: 1/sqrt(64) * log2(e)  (flash uses raw v_exp_f32 = 2^x)
#define QSCALE 0.180336880977f

__global__ __launch_bounds__(256) void gemm_qkv_kernel(
    const short* __restrict__ x2b, const short* __restrict__ xb,
    const short* __restrict__ WqT, const short* __restrict__ WkT,
    const short* __restrict__ WvT,
    const float* __restrict__ bq, const float* __restrict__ bk,
    const float* __restrict__ bv,
    short* __restrict__ Qb, short* __restrict__ Kb, short* __restrict__ VT)
{
    __shared__ short Ls[2 * 16384];     // 64 KB, shared by all MODE branches
    const int z = blockIdx.z;
    if (z == 0) {
        gemm_core<0>(Ls, x2b, WqT, bq, Qb, blockIdx.x * 128, blockIdx.y * 128, QSCALE);
    } else if (z == 1) {
        gemm_core<0>(Ls, xb, WkT, bk, Kb, blockIdx.x * 128, blockIdx.y * 128, 1.0f);
    } else {
        gemm_core<2>(Ls, xb, WvT, bv, VT, blockIdx.x * 128, blockIdx.y * 128, 1.0f);
    }
}

// ---------------------------------------------------------------------------
// gemm_out: 64x128 tiles -> grid (64,8) = 512 blocks = 2 blocks/CU.
// Double-buffer + one-barrier-per-K-step pipeline (R7/R9 verified).
// R14 lesson: 64x64 tiles (4 blocks/CU) regressed ~4 us — keep 64x128.
// ---------------------------------------------------------------------------
__device__ __forceinline__ void gout_stage(
    short* __restrict__ Asb, short* __restrict__ Bsb,
    const short* __restrict__ A, const short* __restrict__ Bw,
    int r0, int n0, int k0c, int w, int srow, int sc)
{
    #pragma unroll
    for (int j = 0; j < 6; j++) {           // 24 issues: 8 A + 16 B
        int q = w * 6 + j;
        if (q < 8) {
            int row = q * 8 + srow;
            gll16(A + ((long)(r0 + row) << 10) + k0c + sc * 8, Asb + q * 512);
        } else {
            int qb = q - 8;
            int row = qb * 8 + srow;
            gll16(Bw + ((long)(n0 + row) << 10) + k0c + sc * 8, Bsb + qb * 512);
        }
    }
}

__global__ __launch_bounds__(256) void gemm_out_kernel(
    const short* __restrict__ A, const short* __restrict__ Bw,
    const float* __restrict__ bias, float* __restrict__ outp)
{
    __shared__ short Ls[2 * 12288];     // 48 KB

    const int r0   = blockIdx.x * 64;
    const int n0   = blockIdx.y * 128;
    const int t    = threadIdx.x;
    const int w    = t >> 6;
    const int ln   = t & 63;
    const int l15  = ln & 15;
    const int quad = ln >> 4;
    const int wr   = w >> 1;            // row group (32 rows)
    const int wc   = w & 1;             // col group (64 cols)

    f32x4 acc[2][4];
    #pragma unroll
    for (int i = 0; i < 2; i++)
        #pragma unroll
        for (int j = 0; j < 4; j++) acc[i][j] = (f32x4){0.f, 0.f, 0.f, 0.f};

    const int srow = ln >> 3;
    const int sc   = (ln & 7) ^ srow;
    const int rsw  = l15 & 7;

    gout_stage(Ls, Ls + 4096, A, Bw, r0, n0, 0, w, srow, sc);

    int cur = 0;
    for (int k0 = 0; k0 < 1024; k0 += 64) {
        __syncthreads();
        if (k0 + 64 < 1024) {
            short* Anx = Ls + (cur ^ 1) * 12288;
            gout_stage(Anx, Anx + 4096, A, Bw, r0, n0, k0 + 64, w, srow, sc);
        }
        const short* Asb = Ls + cur * 12288;
        const short* Bsb = Asb + 4096;
        #pragma unroll
        for (int kh = 0; kh < 2; kh++) {
            int pc = ((kh * 4 + quad) ^ rsw) * 8;
            bf16x8 af[2], bfr[4];
            #pragma unroll
            for (int i = 0; i < 2; i++)
                af[i] = *(const bf16x8*)&Asb[(wr * 32 + i * 16 + l15) * 64 + pc];
            #pragma unroll
            for (int j = 0; j < 4; j++)
                bfr[j] = *(const bf16x8*)&Bsb[(wc * 64 + j * 16 + l15) * 64 + pc];
            #pragma unroll
            for (int i = 0; i < 2; i++)
                #pragma unroll
                for (int j = 0; j < 4; j++)
                    acc[i][j] = __builtin_amdgcn_mfma_f32_16x16x32_bf16(
                        af[i], bfr[j], acc[i][j], 0, 0, 0);
        }
        cur ^= 1;
    }

    #pragma unroll
    for (int j = 0; j < 4; j++) {
        int col = n0 + wc * 64 + j * 16 + l15;
        float bv = bias[col];
        #pragma unroll
        for (int i = 0; i < 2; i++) {
            int rowb = r0 + wr * 32 + i * 16 + quad * 4;
            #pragma unroll
            for (int r = 0; r < 4; r++)
                outp[(long)(rowb + r) * 1024 + col] = acc[i][j][r] + bv;
        }
    }
}

// ---------------------------------------------------------------------------
// MFMA flash attention (R9 verified config — 45.8 us):
// 32 q rows/wave (2 q-groups), 256-thread 4-wave blocks, KVBLK=128,
// register-prefetch pipeline + rotated P5 + XCD swizzle.
// R10: 64 q/wave regressed (57.6). R13: 2-wave/KVBLK=64 regressed (56.5).
// This is the converged structure.
// ---------------------------------------------------------------------------
__global__ __launch_bounds__(256, 2) void flash_kernel(
    const short* __restrict__ Q, const short* __restrict__ K,
    const short* __restrict__ VT, short* __restrict__ O)
{
    const int t    = threadIdx.x;
    const int wave = t >> 6;
    const int ln   = t & 63;
    const int l15  = ln & 15;
    const int quad = ln >> 4;
    // XCD swizzle (bijective, 512 % 8 == 0): 64 consecutive work-ids
    // (= 4 complete bh) per XCD -> 2 MB K/V in the 4 MB XCD L2.
    const int f   = blockIdx.x + (blockIdx.y << 4);
    const int wid = ((f & 7) << 6) | (f >> 3);
    const int bh  = wid >> 4;
    const int b   = bh >> 4;
    const int h   = bh & 15;
    const int q0  = (wid & 15) * 128;
    const int wq  = q0 + wave * 32;         // this wave's first q row

    __shared__ short Ks[2][2][64 * 64];     // [buf][half][kpos][d]
    __shared__ short Vs[2][2][64 * 64];     // [buf][half][d][kpos(sigma)]

    const int srow = ln >> 3;               // row within 8-row staging chunk
    const int sc   = (ln & 7) ^ srow;       // swizzled source chunk (16B)
    const int rsw  = l15 & 7;               // read-side swizzle key
    const int pc0  = ((quad    ) ^ rsw) * 8;
    const int pc1  = ((quad + 4) ^ rsw) * 8;
    const int rb   = l15 * 64;              // fragment row base

    // Q B-frags (pre-scaled by 0.125*log2e): 2 q-groups
    bf16x8 aQ0[2], aQ1[2];
    #pragma unroll
    for (int qg = 0; qg < 2; qg++) {
        const short* Qp = Q + ((long)(b * SQ_ + wq + qg * 16 + l15)) * 1024
                            + h * 64 + quad * 8;
        aQ0[qg] = *(const bf16x8*)(Qp);
        aQ1[qg] = *(const bf16x8*)(Qp + 32);
    }

    bf16x8 ones;
    #pragma unroll
    for (int j = 0; j < 8; j++) ones[j] = (short)0x3F80;   // bf16 1.0

    const f32x4 fz = (f32x4){0.f, 0.f, 0.f, 0.f};   // shared zero C-in

    f32x4 o_acc[2][4];
    f32x4 l_acc[2];
    #pragma unroll
    for (int qg = 0; qg < 2; qg++) {
        l_acc[qg] = fz;
        #pragma unroll
        for (int i = 0; i < 4; i++) o_acc[qg][i] = fz;
    }

    const short* Kbase = K  + ((long)b * SK_) * 1024 + h * 64;
    const short* Vbase = VT + (long)bh * D_ * SK_;
    const int qqa = wave * 2, qqb = wave * 2 + 1;
    const int rowa = qqa * 8 + srow, rowb_ = qqb * 8 + srow;

    // stage one 64-k half-tile into (buf, half)
    #define STAGE(bufp, half, kbase)                                            \
        gll16(Kbase + (long)((kbase) + rowa)  * 1024 + sc * 8,                  \
              &Ks[bufp][half][qqa * 512]);                                      \
        gll16(Kbase + (long)((kbase) + rowb_) * 1024 + sc * 8,                  \
              &Ks[bufp][half][qqb * 512]);                                      \
        gll16(Vbase + (long)rowa  * 2048 + (kbase) + sc * 8,                    \
              &Vs[bufp][half][qqa * 512]);                                      \
        gll16(Vbase + (long)rowb_ * 2048 + (kbase) + sc * 8,                    \
              &Vs[bufp][half][qqb * 512]);

    // prologue: stage k-tile pair 0 into buffer 0
    STAGE(0, 0, 0)
    STAGE(0, 1, 64)

    // loop-carried deferred-P5 state (written in P4, consumed next iter)
    u32 pwB[2][8];
    bf16x8 vfB[8];

    int cur = 0;
    for (int k0 = 0; k0 < SK_; k0 += 128) {
        __syncthreads();
        if (k0 + 128 < SK_) {
            int nx = cur ^ 1;
            STAGE(nx, 0, k0 + 128)
            STAGE(nx, 1, k0 + 192)
        }
        const short* K0 = &Ks[cur][0][0];
        const short* K1 = &Ks[cur][1][0];
        const short* V0 = &Vs[cur][0][0];
        const short* V1 = &Vs[cur][1][0];

        // ---- P0: issue K0 fragment reads ----
        bf16x8 kfA[8];
        #pragma unroll
        for (int kt = 0; kt < 4; kt++) {
            const short* kr = &K0[kt * 1024 + rb];
            kfA[kt * 2    ] = *(const bf16x8*)&kr[pc0];
            kfA[kt * 2 + 1] = *(const bf16x8*)&kr[pc1];
        }

        // ---- P5 of PREVIOUS iteration (registers only): hides K0 reads ----
        if (k0) {
            bf16x8 aP0B[2], aP1B[2];
            #pragma unroll
            for (int qg = 0; qg < 2; qg++) {
                union { bf16x8 v; u32 w[4]; } u0, u1;
                u0.w[0] = pwB[qg][0]; u0.w[1] = pwB[qg][1];
                u0.w[2] = pwB[qg][2]; u0.w[3] = pwB[qg][3];
                u1.w[0] = pwB[qg][4]; u1.w[1] = pwB[qg][5];
                u1.w[2] = pwB[qg][6]; u1.w[3] = pwB[qg][7];
                aP0B[qg] = u0.v; aP1B[qg] = u1.v;
            }
            __builtin_amdgcn_s_setprio(1);
            #pragma unroll
            for (int qg = 0; qg < 2; qg++) {
                l_acc[qg] = __builtin_amdgcn_mfma_f32_16x16x32_bf16(aP0B[qg], ones, l_acc[qg], 0, 0, 0);
                l_acc[qg] = __builtin_amdgcn_mfma_f32_16x16x32_bf16(aP1B[qg], ones, l_acc[qg], 0, 0, 0);
            }
            #pragma unroll
            for (int dt = 0; dt < 4; dt++) {
                #pragma unroll
                for (int qg = 0; qg < 2; qg++) {
                    o_acc[qg][dt] = __builtin_amdgcn_mfma_f32_16x16x32_bf16(aP0B[qg], vfB[dt * 2    ], o_acc[qg][dt], 0, 0, 0);
                    o_acc[qg][dt] = __builtin_amdgcn_mfma_f32_16x16x32_bf16(aP1B[qg], vfB[dt * 2 + 1], o_acc[qg][dt], 0, 0, 0);
                }
            }
            __builtin_amdgcn_s_setprio(0);
        }

        // ---- P1: issue K1 reads; QK half0 off kfA ----
        bf16x8 kfB[8];
        #pragma unroll
        for (int kt = 0; kt < 4; kt++) {
            const short* kr = &K1[kt * 1024 + rb];
            kfB[kt * 2    ] = *(const bf16x8*)&kr[pc0];
            kfB[kt * 2 + 1] = *(const bf16x8*)&kr[pc1];
        }
        f32x4 zA[2][4], zB[2][4];
        #pragma unroll
        for (int kt = 0; kt < 4; kt++)
            #pragma unroll
            for (int qg = 0; qg < 2; qg++) {
                f32x4 z = __builtin_amdgcn_mfma_f32_16x16x32_bf16(kfA[kt * 2], aQ0[qg], fz, 0, 0, 0);
                zA[qg][kt] = __builtin_amdgcn_mfma_f32_16x16x32_bf16(kfA[kt * 2 + 1], aQ1[qg], z, 0, 0, 0);
            }

        // ---- P2: issue V0 reads; QK half1 (kfB) ∥ exp2+pack half0 ----
        bf16x8 vfA[8];
        #pragma unroll
        for (int dt = 0; dt < 4; dt++) {
            const short* vr = &V0[dt * 1024 + rb];
            vfA[dt * 2    ] = *(const bf16x8*)&vr[pc0];
            vfA[dt * 2 + 1] = *(const bf16x8*)&vr[pc1];
        }
        u32 pwA[2][8];
        #pragma unroll
        for (int kt = 0; kt < 4; kt++) {
            #pragma unroll
            for (int qg = 0; qg < 2; qg++) {
                f32x4 z = __builtin_amdgcn_mfma_f32_16x16x32_bf16(kfB[kt * 2], aQ0[qg], fz, 0, 0, 0);
                zB[qg][kt] = __builtin_amdgcn_mfma_f32_16x16x32_bf16(kfB[kt * 2 + 1], aQ1[qg], z, 0, 0, 0);
            }
            #pragma unroll
            for (int qg = 0; qg < 2; qg++) {
                f32x4 s = zA[qg][kt];
                pwA[qg][kt * 2    ] = pkbf_rh(__builtin_amdgcn_exp2f(s[0]),
                                              __builtin_amdgcn_exp2f(s[1]));
                pwA[qg][kt * 2 + 1] = pkbf_rh(__builtin_amdgcn_exp2f(s[2]),
                                              __builtin_amdgcn_exp2f(s[3]));
            }
        }

        // ---- P3: aP(half0) + l(half0) ----
        bf16x8 aP0A[2], aP1A[2];
        #pragma unroll
        for (int qg = 0; qg < 2; qg++) {
            union { bf16x8 v; u32 w[4]; } u0, u1;
            u0.w[0] = pwA[qg][0]; u0.w[1] = pwA[qg][1];
            u0.w[2] = pwA[qg][2]; u0.w[3] = pwA[qg][3];
            u1.w[0] = pwA[qg][4]; u1.w[1] = pwA[qg][5];
            u1.w[2] = pwA[qg][6]; u1.w[3] = pwA[qg][7];
            aP0A[qg] = u0.v; aP1A[qg] = u1.v;
            l_acc[qg] = __builtin_amdgcn_mfma_f32_16x16x32_bf16(aP0A[qg], ones, l_acc[qg], 0, 0, 0);
            l_acc[qg] = __builtin_amdgcn_mfma_f32_16x16x32_bf16(aP1A[qg], ones, l_acc[qg], 0, 0, 0);
        }

        // ---- P4: issue V1 reads; PV half0 (vfA) ∥ exp2+pack half1 -> pwB ----
        #pragma unroll
        for (int dt = 0; dt < 4; dt++) {
            const short* vr = &V1[dt * 1024 + rb];
            vfB[dt * 2    ] = *(const bf16x8*)&vr[pc0];
            vfB[dt * 2 + 1] = *(const bf16x8*)&vr[pc1];
        }
        #pragma unroll
        for (int dt = 0; dt < 4; dt++) {
            #pragma unroll
            for (int qg = 0; qg < 2; qg++) {
                o_acc[qg][dt] = __builtin_amdgcn_mfma_f32_16x16x32_bf16(aP0A[qg], vfA[dt * 2    ], o_acc[qg][dt], 0, 0, 0);
                o_acc[qg][dt] = __builtin_amdgcn_mfma_f32_16x16x32_bf16(aP1A[qg], vfA[dt * 2 + 1], o_acc[qg][dt], 0, 0, 0);
            }
            #pragma unroll
            for (int qg = 0; qg < 2; qg++) {
                f32x4 s = zB[qg][dt];
                pwB[qg][dt * 2    ] = pkbf_rh(__builtin_amdgcn_exp2f(s[0]),
                                              __builtin_amdgcn_exp2f(s[1]));
                pwB[qg][dt * 2 + 1] = pkbf_rh(__builtin_amdgcn_exp2f(s[2]),
                                              __builtin_amdgcn_exp2f(s[3]));
            }
        }
        cur ^= 1;
    }
    #undef STAGE

    // ---- final deferred P5 ----
    {
        bf16x8 aP0B[2], aP1B[2];
        #pragma unroll
        for (int qg = 0; qg < 2; qg++) {
            union { bf16x8 v; u32 w[4]; } u0, u1;
            u0.w[0] = pwB[qg][0]; u0.w[1] = pwB[qg][1];
            u0.w[2] = pwB[qg][2]; u0.w[3] = pwB[qg][3];
            u1.w[0] = pwB[qg][4]; u1.w[1] = pwB[qg][5];
            u1.w[2] = pwB[qg][6]; u1.w[3] = pwB[qg][7];
            aP0B[qg] = u0.v; aP1B[qg] = u1.v;
            l_acc[qg] = __builtin_amdgcn_mfma_f32_16x16x32_bf16(aP0B[qg], ones, l_acc[qg], 0, 0, 0);
            l_acc[qg] = __builtin_amdgcn_mfma_f32_16x16x32_bf16(aP1B[qg], ones, l_acc[qg], 0, 0, 0);
        }
        #pragma unroll
        for (int dt = 0; dt < 4; dt++) {
            #pragma unroll
            for (int qg = 0; qg < 2; qg++) {
                o_acc[qg][dt] = __builtin_amdgcn_mfma_f32_16x16x32_bf16(aP0B[qg], vfB[dt * 2    ], o_acc[qg][dt], 0, 0, 0);
                o_acc[qg][dt] = __builtin_amdgcn_mfma_f32_16x16x32_bf16(aP1B[qg], vfB[dt * 2 + 1], o_acc[qg][dt], 0, 0, 0);
            }
        }
    }

    // --- epilogue: normalize, write head-concat bf16 (col l15 = d) ---
    #pragma unroll
    for (int qg = 0; qg < 2; qg++) {
        #pragma unroll
        for (int r = 0; r < 4; r++) {
            float inv = 1.0f / l_acc[qg][r];
            long row = (long)b * SQ_ + wq + qg * 16 + quad * 4 + r;
            short* Op = O + row * 1024 + h * 64 + l15;
            #pragma unroll
            for (int dt = 0; dt < 4; dt++)
                Op[dt * 16] = f2bf(o_acc[qg][dt][r] * inv);
        }
    }
}

extern "C" void kernel_launch(void* const* d_in, const int* in_sizes, int n_in,
                              void* d_out, int out_size, void* d_ws, size_t ws_size,
                              hipStream_t stream) {
    const float* x  = (const float*)d_in[0];
    const float* x2 = (const float*)d_in[1];
    const float* Wq = (const float*)d_in[2];
    const float* bq = (const float*)d_in[3];
    const float* Wk = (const float*)d_in[4];
    const float* bk = (const float*)d_in[5];
    const float* Wv = (const float*)d_in[6];
    const float* bv = (const float*)d_in[7];
    const float* Wo = (const float*)d_in[8];
    const float* bo = (const float*)d_in[9];
    float* out = (float*)d_out;

    const size_t nAct = (size_t)B_ * SK_ * DM_;    // 4,194,304
    const size_t nW   = (size_t)DM_ * DM_;         // 1,048,576
    short* bufA = (short*)d_ws;        // xb
    short* bufB = bufA + nAct;         // x2b, later O (bf16)
    short* Qb   = bufB + nAct;
    short* Kb   = Qb + nAct;
    short* VTws = Kb + nAct;           // V written directly in VT layout (sigma-permuted)
    short* WqT  = VTws + nAct;
    short* WkT  = WqT + nW;
    short* WvT  = WkT + nW;
    short* Wob  = WvT + nW;
    // total 5*nAct + 4*nW shorts = 50 MiB

    prep_kernel<<<dim3(16, 16, 6), 256, 0, stream>>>(
        Wq, Wk, Wv, Wo, x, x2, WqT, WkT, WvT, Wob, bufA, bufB);

    gemm_qkv_kernel<<<dim3(32, 8, 3), 256, 0, stream>>>(
        bufB, bufA, WqT, WkT, WvT, bq, bk, bv, Qb, Kb, VTws);

    flash_kernel<<<dim3(16, 32), 256, 0, stream>>>(Qb, Kb, VTws, bufB); // bufB = O
    gemm_out_kernel<<<dim3(64, 8), 256, 0, stream>>>(bufB, Wob, bo, out);
}